// Round 4
// baseline (659.325 us; speedup 1.0000x reference)
//
#include <hip/hip_runtime.h>
#include <stdint.h>

// Instant-NGP HashGrid forward, MI355X. Gather-bound.
// R4: revert nontemporal (nt bypassed L2 -> FETCH 440MB->2.5GB, 2.3x dur).
// R5: baseline 394us kernel; VGPR=28, VALUBusy 12.5%, HBM 18%, all pipes
//     <40% -> latency-bound, ILP-starved.
// R6 FAILED: full unroll -> VGPR 32, compiler refuses cross-level hoisting.
// R7 FAILED: manual issue/consume split -> compiler SANK loads back to the
//     consume site (VGPR=44, not ~100) + occupancy 40% -> 510us.
// R8: pin the pipeline with sched_barrier(0) after every issue group so the
//     scheduler cannot sink the gathers. Depth-2 rotation, 8 unconditional
//     dwordx2 gathers per level (no divergent partner branch). R5's 16KB
//     two-half LDS shell. launch_bounds(256,6): ~80 VGPR budget, 24
//     waves/CU (75%) -- room for 2x19-reg level state without spill.

#define NLVL 16
#define TS 65536
#define P2 2654435761u
#define P3 805459861u

typedef float v4f __attribute__((ext_vector_type(4)));
typedef float v2f __attribute__((ext_vector_type(2)));
// 8-byte-aligned float4 view for dense-path table loads.
typedef float v4fa8 __attribute__((ext_vector_type(4), aligned(8)));

#define SB() __builtin_amdgcn_sched_barrier(0)

__constant__ float C_SCALES[NLVL] = {
    15.0f, 23.0f, 35.0f, 53.0f, 80.0f, 120.5f, 181.25f, 272.375f,
    409.0625f, 614.09375f, 921.640625f, 1382.9609375f,
    2074.94140625f, 3112.912109375f, 4669.8681640625f, 7005.30224609375f};

__device__ __forceinline__ v2f v4lo8(v4fa8 v) { v2f r; r.x = v.x; r.y = v.y; return r; }
__device__ __forceinline__ v2f v4hi8(v4fa8 v) { v2f r; r.x = v.z; r.y = v.w; return r; }

// Half-tile: [256 pts][4 float4 slots]; within-half group gl, half-bit h;
// slot(p,gl) = (gl+p)&3.
__device__ __forceinline__ void lds_put2(float* s, int p, int gl, int h,
                                         float a, float b) {
    const int slot = (gl + p) & 3;
    const int a32 = p * 16 + slot * 4 + h * 2;  // 8B-aligned
    s[a32] = a;
    s[a32 + 1] = b;
}

// Pipeline state for one hashed level: 8 corner features + fracs (19 VGPR).
struct LvlS {
    v2f c0, c1, c2, c3, c4, c5, c6, c7;
    float wx, wy, wz;
};

__device__ __forceinline__ void lvl_issue(LvlS& s, float px, float py,
                                          float pz, float scale,
                                          const v2f* __restrict__ tbl) {
    const float fx = px * scale + 0.5f;
    const float fy = py * scale + 0.5f;
    const float fz = pz * scale + 0.5f;
    const float gx = floorf(fx), gy = floorf(fy), gz = floorf(fz);
    s.wx = fx - gx;
    s.wy = fy - gy;
    s.wz = fz - gz;
    const uint32_t bx = (uint32_t)(int)gx, bx1 = bx + 1;
    const uint32_t hy0 = (uint32_t)(int)gy * P2, hy1 = hy0 + P2;
    const uint32_t hz0 = (uint32_t)(int)gz * P3, hz1 = hz0 + P3;
    const uint32_t b00 = hy0 ^ hz0, b01 = hy0 ^ hz1;
    const uint32_t b10 = hy1 ^ hz0, b11 = hy1 ^ hz1;
    s.c0 = tbl[(bx ^ b00) & (TS - 1)];
    s.c1 = tbl[(bx ^ b01) & (TS - 1)];
    s.c2 = tbl[(bx ^ b10) & (TS - 1)];
    s.c3 = tbl[(bx ^ b11) & (TS - 1)];
    s.c4 = tbl[(bx1 ^ b00) & (TS - 1)];
    s.c5 = tbl[(bx1 ^ b01) & (TS - 1)];
    s.c6 = tbl[(bx1 ^ b10) & (TS - 1)];
    s.c7 = tbl[(bx1 ^ b11) & (TS - 1)];
}

__device__ __forceinline__ v2f lvl_consume(const LvlS& s) {
    const float ux = 1.0f - s.wx, uy = 1.0f - s.wy, uz = 1.0f - s.wz;
    const float w0 = ux * uy * uz, w1 = ux * uy * s.wz;
    const float w2 = ux * s.wy * uz, w3 = ux * s.wy * s.wz;
    const float w4 = s.wx * uy * uz, w5 = s.wx * uy * s.wz;
    const float w6 = s.wx * s.wy * uz, w7 = s.wx * s.wy * s.wz;
    v2f o;
    o.x = w0 * s.c0.x + w1 * s.c1.x + w2 * s.c2.x + w3 * s.c3.x +
          w4 * s.c4.x + w5 * s.c5.x + w6 * s.c6.x + w7 * s.c7.x;
    o.y = w0 * s.c0.y + w1 * s.c1.y + w2 * s.c2.y + w3 * s.c3.y +
          w4 * s.c4.y + w5 * s.c5.y + w6 * s.c6.y + w7 * s.c7.y;
    return o;
}

__global__ __launch_bounds__(256, 6) void hashgrid_fwd(
    const float* __restrict__ x,
    const float* __restrict__ table,
    float* __restrict__ out,
    int n)
{
    __shared__ float s_out[256 * 16];  // 16 KiB half-tile

    const int tid0 = blockIdx.x * 256 + threadIdx.x;
    const int tid = min(tid0, n - 1);
    const int p = threadIdx.x;

    const float px = x[3 * tid + 0];
    const float py = x[3 * tid + 1];
    const float pz = x[3 * tid + 2];

    v4f* outb4 = (v4f*)out + (size_t)blockIdx.x * (256 * 8);
    const long long lim4 = (long long)n * 8 - (long long)blockIdx.x * (256 * 8);

    const v2f* tblv = (const v2f*)table;

    // consume level L of the current half (hl = L>>1 within-half group base)
#define STEP_H0(S, L) { const v2f o = lvl_consume(S); \
                        lds_put2(s_out, p, (L) >> 1, (L) & 1, o.x, o.y); }
#define STEP_H1(S, L) { const v2f o = lvl_consume(S); \
                        lds_put2(s_out, p, ((L) >> 1) - 4, (L) & 1, o.x, o.y); }
#define ISSUE(S, L) lvl_issue(S, px, py, pz, C_SCALES[L], \
                              tblv + (size_t)(L) * TS); SB();

    // ---- prime the pipeline: levels 3,4 in flight (pinned) ----
    LvlS s0, s1;
    ISSUE(s0, 3)
    ISSUE(s1, 4)

    // ---- dense levels 0..2 (small tables, L2-hot) cover the first trip ----
    {
        const int RESO[3] = {16, 24, 36};
        const float DSC[3] = {15.0f, 23.0f, 35.0f};
#pragma unroll
        for (int l = 0; l < 3; ++l) {
            const float scale = DSC[l];
            const float fx = px * scale + 0.5f;
            const float fy = py * scale + 0.5f;
            const float fz = pz * scale + 0.5f;
            const float gx = floorf(fx), gy = floorf(fy), gz = floorf(fz);
            const float wx = fx - gx, wy = fy - gy, wz = fz - gz;
            const int ix = (int)gx, iy = (int)gy, iz = (int)gz;

            const v2f* tbl = tblv + (size_t)l * TS;
            const int R = RESO[l];
            const int x0 = min(ix, R - 1);
            const int y0 = min(iy, R - 1), y1 = min(iy + 1, R - 1);
            const int z0 = min(iz, R - 1), z1 = min(iz + 1, R - 1);
            const int xb = min(x0, R - 2);
            const bool hi0 = (x0 != xb);
            const int y0R = y0 * R, y1R = y1 * R;
            const int z0R = z0 * R * R, z1R = z1 * R * R;
            const v4fa8 f00 = *(const v4fa8*)(tbl + (xb + y0R + z0R));
            const v4fa8 f01 = *(const v4fa8*)(tbl + (xb + y0R + z1R));
            const v4fa8 f10 = *(const v4fa8*)(tbl + (xb + y1R + z0R));
            const v4fa8 f11 = *(const v4fa8*)(tbl + (xb + y1R + z1R));
            const v2f c0 = hi0 ? v4hi8(f00) : v4lo8(f00), c4 = v4hi8(f00);
            const v2f c1 = hi0 ? v4hi8(f01) : v4lo8(f01), c5 = v4hi8(f01);
            const v2f c2 = hi0 ? v4hi8(f10) : v4lo8(f10), c6 = v4hi8(f10);
            const v2f c3 = hi0 ? v4hi8(f11) : v4lo8(f11), c7 = v4hi8(f11);

            const float ux = 1.0f - wx, uy = 1.0f - wy, uz = 1.0f - wz;
            const float w0 = ux * uy * uz, w1 = ux * uy * wz;
            const float w2 = ux * wy * uz, w3 = ux * wy * wz;
            const float w4 = wx * uy * uz, w5 = wx * uy * wz;
            const float w6 = wx * wy * uz, w7 = wx * wy * wz;

            const float o0 = w0 * c0.x + w1 * c1.x + w2 * c2.x + w3 * c3.x +
                             w4 * c4.x + w5 * c5.x + w6 * c6.x + w7 * c7.x;
            const float o1 = w0 * c0.y + w1 * c1.y + w2 * c2.y + w3 * c3.y +
                             w4 * c4.y + w5 * c5.y + w6 * c6.y + w7 * c7.y;
            lds_put2(s_out, p, l >> 1, l & 1, o0, o1);
        }
    }

    // ---- half 0 rotation: consume 3..7, keep 2 levels in flight ----
    STEP_H0(s0, 3) ISSUE(s0, 5)
    STEP_H0(s1, 4) ISSUE(s1, 6)
    STEP_H0(s0, 5) ISSUE(s0, 7)
    STEP_H0(s1, 6) ISSUE(s1, 8)   // prefetch into half 1 across the barrier
    STEP_H0(s0, 7) ISSUE(s0, 9)

    __syncthreads();
    // store half 0: features 0..15 of each point = full 64B lines
#pragma unroll
    for (int r = 0; r < 4; ++r) {
        const int e = r * 256 + threadIdx.x;   // 0..1023
        const int pp = e >> 2, g = e & 3;
        const int slot = (g + pp) & 3;
        const v4f v = *(const v4f*)&s_out[pp * 16 + slot * 4];
        const int o4 = pp * 8 + g;             // first half of point pp
        if (o4 < lim4) outb4[o4] = v;
    }
    __syncthreads();

    // ---- half 1 rotation: consume 8..15 ----
    STEP_H1(s1, 8)  ISSUE(s1, 10)
    STEP_H1(s0, 9)  ISSUE(s0, 11)
    STEP_H1(s1, 10) ISSUE(s1, 12)
    STEP_H1(s0, 11) ISSUE(s0, 13)
    STEP_H1(s1, 12) ISSUE(s1, 14)
    STEP_H1(s0, 13) ISSUE(s0, 15)
    STEP_H1(s1, 14)
    STEP_H1(s0, 15)

    __syncthreads();
    // store half 1: features 16..31
#pragma unroll
    for (int r = 0; r < 4; ++r) {
        const int e = r * 256 + threadIdx.x;
        const int pp = e >> 2, g = e & 3;
        const int slot = (g + pp) & 3;
        const v4f v = *(const v4f*)&s_out[pp * 16 + slot * 4];
        const int o4 = pp * 8 + 4 + g;         // second half of point pp
        if (o4 < lim4) outb4[o4] = v;
    }

#undef STEP_H0
#undef STEP_H1
#undef ISSUE
}

extern "C" void kernel_launch(void* const* d_in, const int* in_sizes, int n_in,
                              void* d_out, int out_size, void* d_ws, size_t ws_size,
                              hipStream_t stream) {
    const float* x = (const float*)d_in[0];     // [N,3] f32
    const float* table = (const float*)d_in[1]; // [16,65536,2] f32
    float* out = (float*)d_out;                 // [N,32] f32
    const int n = in_sizes[0] / 3;
    const int block = 256;
    const int grid = (n + block - 1) / block;
    hashgrid_fwd<<<grid, block, 0, stream>>>(x, table, out, n);
}

// Round 5
// 520.440 us; speedup vs baseline: 1.2669x; 1.2669x over previous
//
#include <hip/hip_runtime.h>
#include <stdint.h>

// Instant-NGP HashGrid forward, MI355X. Gather-bound.
// R4: revert nontemporal (nt bypassed L2 -> FETCH 440MB->2.5GB, 2.3x dur).
// R5: baseline 394us kernel; VGPR=28, VALUBusy 12.5%, HBM 18%, all pipes
//     <40% -> latency-bound.
// R6 FAILED: full unroll -> compiler refuses cross-level load hoisting.
// R7 FAILED: manual issue/consume split -> compiler sank loads (510us).
// R8 FAILED: sched_barrier-pinned pipeline -> regalloc SPILLED level state
//     (WRITE 131->337MB scratch traffic, 565us). Conclusion: per-wave ILP
//     is unraisable on this compiler for this kernel.
// R9: XCD level-affinity split. Blocks round-robin XCDs (bid&7 = XCD, m09).
//     XCDs 0-3 run levels 0-7 (2.5MB hashed tables), XCDs 4-7 run levels
//     8-15 (4MB) -> each XCD's hashed working set fits its private 4MB L2,
//     replacing ~40% L3-latency gathers with L2-latency ones. Each group =
//     one R5 half: 16KB LDS tile, one sync, 64B half-line stores.
//     Arithmetic identical to R5.

#define NLVL 16
#define TS 65536
#define P2 2654435761u
#define P3 805459861u

typedef float v4f __attribute__((ext_vector_type(4)));
typedef float v2f __attribute__((ext_vector_type(2)));
// 8-byte-aligned float4 view for dense-path table loads.
typedef float v4fa8 __attribute__((ext_vector_type(4), aligned(8)));

__constant__ float C_SCALES[NLVL] = {
    15.0f, 23.0f, 35.0f, 53.0f, 80.0f, 120.5f, 181.25f, 272.375f,
    409.0625f, 614.09375f, 921.640625f, 1382.9609375f,
    2074.94140625f, 3112.912109375f, 4669.8681640625f, 7005.30224609375f};

__device__ __forceinline__ v2f v4lo(v4f v) { v2f r; r.x = v.x; r.y = v.y; return r; }
__device__ __forceinline__ v2f v4hi(v4f v) { v2f r; r.x = v.z; r.y = v.w; return r; }
__device__ __forceinline__ v2f v4lo8(v4fa8 v) { v2f r; r.x = v.x; r.y = v.y; return r; }
__device__ __forceinline__ v2f v4hi8(v4fa8 v) { v2f r; r.x = v.z; r.y = v.w; return r; }

// Half-tile: [256 pts][4 float4 slots]; within-half group gl, half-bit h;
// slot(p,gl) = (gl+p)&3.
__device__ __forceinline__ void lds_put2(float* s, int p, int gl, int h,
                                         float a, float b) {
    const int slot = (gl + p) & 3;
    const int a32 = p * 16 + slot * 4 + h * 2;  // 8B-aligned
    s[a32] = a;
    s[a32 + 1] = b;
}

// One hashed level: returns interpolated (f0,f1). R5 version: 4 v4f loads
// + 4 conditional v2f partner loads (avg 6 line-requests/level).
__device__ __forceinline__ v2f hashed_level(float px, float py, float pz,
                                            float scale, const v2f* tbl) {
    const float fx = px * scale + 0.5f;
    const float fy = py * scale + 0.5f;
    const float fz = pz * scale + 0.5f;
    const float gx = floorf(fx), gy = floorf(fy), gz = floorf(fz);
    const float wx = fx - gx, wy = fy - gy, wz = fz - gz;
    const int ix = (int)gx, iy = (int)gy, iz = (int)gz;

    // h = x ^ y*P2 ^ z*P3 ; even x: h(x+1)=h(x)^1 -> same aligned float4 pair
    const uint32_t bx = (uint32_t)ix;
    const uint32_t hy0 = (uint32_t)iy * P2, hy1 = hy0 + P2;
    const uint32_t hz0 = (uint32_t)iz * P3, hz1 = hz0 + P3;
    const uint32_t b00 = hy0 ^ hz0, b01 = hy0 ^ hz1;
    const uint32_t b10 = hy1 ^ hz0, b11 = hy1 ^ hz1;
    const uint32_t i00 = (bx ^ b00) & (TS - 1);
    const uint32_t i01 = (bx ^ b01) & (TS - 1);
    const uint32_t i10 = (bx ^ b10) & (TS - 1);
    const uint32_t i11 = (bx ^ b11) & (TS - 1);
    const v4f* tbl4 = (const v4f*)tbl;
    const v4f f00 = tbl4[i00 >> 1];
    const v4f f01 = tbl4[i01 >> 1];
    const v4f f10 = tbl4[i10 >> 1];
    const v4f f11 = tbl4[i11 >> 1];
    const v2f c0 = (i00 & 1) ? v4hi(f00) : v4lo(f00);
    const v2f c1 = (i01 & 1) ? v4hi(f01) : v4lo(f01);
    const v2f c2 = (i10 & 1) ? v4hi(f10) : v4lo(f10);
    const v2f c3 = (i11 & 1) ? v4hi(f11) : v4lo(f11);
    v2f c4, c5, c6, c7;
    if ((ix & 1) == 0) {
        c4 = (i00 & 1) ? v4lo(f00) : v4hi(f00);
        c5 = (i01 & 1) ? v4lo(f01) : v4hi(f01);
        c6 = (i10 & 1) ? v4lo(f10) : v4hi(f10);
        c7 = (i11 & 1) ? v4lo(f11) : v4hi(f11);
    } else {
        const uint32_t bx1 = bx + 1;
        c4 = tbl[(bx1 ^ b00) & (TS - 1)];
        c5 = tbl[(bx1 ^ b01) & (TS - 1)];
        c6 = tbl[(bx1 ^ b10) & (TS - 1)];
        c7 = tbl[(bx1 ^ b11) & (TS - 1)];
    }

    const float ux = 1.0f - wx, uy = 1.0f - wy, uz = 1.0f - wz;
    const float w0 = ux * uy * uz, w1 = ux * uy * wz;
    const float w2 = ux * wy * uz, w3 = ux * wy * wz;
    const float w4 = wx * uy * uz, w5 = wx * uy * wz;
    const float w6 = wx * wy * uz, w7 = wx * wy * wz;

    v2f o;
    o.x = w0 * c0.x + w1 * c1.x + w2 * c2.x + w3 * c3.x +
          w4 * c4.x + w5 * c5.x + w6 * c6.x + w7 * c7.x;
    o.y = w0 * c0.y + w1 * c1.y + w2 * c2.y + w3 * c3.y +
          w4 * c4.y + w5 * c5.y + w6 * c6.y + w7 * c7.y;
    return o;
}

__global__ __launch_bounds__(256, 8) void hashgrid_fwd(
    const float* __restrict__ x,
    const float* __restrict__ table,
    float* __restrict__ out,
    int n)
{
    __shared__ float s_out[256 * 16];  // 16 KiB half-tile

    // XCD decode: bid&7 = XCD (round-robin dispatch, m09). XCD 0-3 -> group
    // 0 (levels 0-7); XCD 4-7 -> group 1 (levels 8-15). chunk = point tile.
    const int bid = blockIdx.x;
    const int xcd = bid & 7;
    const int grp = (xcd >> 2) & 1;
    const int chunk = (bid >> 3) * 4 + (xcd & 3);
    const int nchunks = (n + 255) >> 8;
    if (chunk >= nchunks) return;

    const int tid0 = chunk * 256 + threadIdx.x;
    const int tid = min(tid0, n - 1);
    const int p = threadIdx.x;

    const float px = x[3 * tid + 0];
    const float py = x[3 * tid + 1];
    const float pz = x[3 * tid + 2];

    v4f* outb4 = (v4f*)out + (size_t)chunk * (256 * 8);
    const long long lim4 = (long long)n * 8 - (long long)chunk * (256 * 8);

    const v2f* tblv = (const v2f*)table;

    if (grp == 0) {
        // ============ levels 0..7 -> features 0..15 ============
        // dense levels 0..2 (small tables, L1/L2-hot), unrolled
        {
            const int RESO[3] = {16, 24, 36};
            const float DSC[3] = {15.0f, 23.0f, 35.0f};
#pragma unroll
            for (int l = 0; l < 3; ++l) {
                const float scale = DSC[l];
                const float fx = px * scale + 0.5f;
                const float fy = py * scale + 0.5f;
                const float fz = pz * scale + 0.5f;
                const float gx = floorf(fx), gy = floorf(fy), gz = floorf(fz);
                const float wx = fx - gx, wy = fy - gy, wz = fz - gz;
                const int ix = (int)gx, iy = (int)gy, iz = (int)gz;

                const v2f* tbl = tblv + (size_t)l * TS;
                const int R = RESO[l];
                const int x0 = min(ix, R - 1);
                const int y0 = min(iy, R - 1), y1 = min(iy + 1, R - 1);
                const int z0 = min(iz, R - 1), z1 = min(iz + 1, R - 1);
                const int xb = min(x0, R - 2);
                const bool hi0 = (x0 != xb);
                const int y0R = y0 * R, y1R = y1 * R;
                const int z0R = z0 * R * R, z1R = z1 * R * R;
                const v4fa8 f00 = *(const v4fa8*)(tbl + (xb + y0R + z0R));
                const v4fa8 f01 = *(const v4fa8*)(tbl + (xb + y0R + z1R));
                const v4fa8 f10 = *(const v4fa8*)(tbl + (xb + y1R + z0R));
                const v4fa8 f11 = *(const v4fa8*)(tbl + (xb + y1R + z1R));
                const v2f c0 = hi0 ? v4hi8(f00) : v4lo8(f00), c4 = v4hi8(f00);
                const v2f c1 = hi0 ? v4hi8(f01) : v4lo8(f01), c5 = v4hi8(f01);
                const v2f c2 = hi0 ? v4hi8(f10) : v4lo8(f10), c6 = v4hi8(f10);
                const v2f c3 = hi0 ? v4hi8(f11) : v4lo8(f11), c7 = v4hi8(f11);

                const float ux = 1.0f - wx, uy = 1.0f - wy, uz = 1.0f - wz;
                const float w0 = ux * uy * uz, w1 = ux * uy * wz;
                const float w2 = ux * wy * uz, w3 = ux * wy * wz;
                const float w4 = wx * uy * uz, w5 = wx * uy * wz;
                const float w6 = wx * wy * uz, w7 = wx * wy * wz;

                const float o0 = w0 * c0.x + w1 * c1.x + w2 * c2.x + w3 * c3.x +
                                 w4 * c4.x + w5 * c5.x + w6 * c6.x + w7 * c7.x;
                const float o1 = w0 * c0.y + w1 * c1.y + w2 * c2.y + w3 * c3.y +
                                 w4 * c4.y + w5 * c5.y + w6 * c6.y + w7 * c7.y;
                lds_put2(s_out, p, l >> 1, l & 1, o0, o1);
            }
        }
        // hashed levels 3..7
#pragma unroll 2
        for (int l = 3; l < 8; ++l) {
            const v2f o = hashed_level(px, py, pz, C_SCALES[l],
                                       tblv + (size_t)l * TS);
            lds_put2(s_out, p, l >> 1, l & 1, o.x, o.y);
        }
        __syncthreads();
        // store features 0..15 of each point = first 64B line
#pragma unroll
        for (int r = 0; r < 4; ++r) {
            const int e = r * 256 + threadIdx.x;   // 0..1023
            const int pp = e >> 2, g = e & 3;
            const int slot = (g + pp) & 3;
            const v4f v = *(const v4f*)&s_out[pp * 16 + slot * 4];
            const int o4 = pp * 8 + g;
            if (o4 < lim4) outb4[o4] = v;
        }
    } else {
        // ============ levels 8..15 -> features 16..31 ============
#pragma unroll 2
        for (int l = 8; l < NLVL; ++l) {
            const v2f o = hashed_level(px, py, pz, C_SCALES[l],
                                       tblv + (size_t)l * TS);
            lds_put2(s_out, p, (l >> 1) - 4, l & 1, o.x, o.y);
        }
        __syncthreads();
        // store features 16..31 of each point = second 64B line
#pragma unroll
        for (int r = 0; r < 4; ++r) {
            const int e = r * 256 + threadIdx.x;
            const int pp = e >> 2, g = e & 3;
            const int slot = (g + pp) & 3;
            const v4f v = *(const v4f*)&s_out[pp * 16 + slot * 4];
            const int o4 = pp * 8 + 4 + g;
            if (o4 < lim4) outb4[o4] = v;
        }
    }
}

extern "C" void kernel_launch(void* const* d_in, const int* in_sizes, int n_in,
                              void* d_out, int out_size, void* d_ws, size_t ws_size,
                              hipStream_t stream) {
    const float* x = (const float*)d_in[0];     // [N,3] f32
    const float* table = (const float*)d_in[1]; // [16,65536,2] f32
    float* out = (float*)d_out;                 // [N,32] f32
    const int n = in_sizes[0] / 3;
    const int nchunks = (n + 255) / 256;
    // 8 blocks per 4 chunks: XCDs 0-3 cover levels 0-7, XCDs 4-7 levels 8-15
    const int grid = 8 * ((nchunks + 3) / 4);
    hashgrid_fwd<<<grid, 256, 0, stream>>>(x, table, out, n);
}

// Round 7
// 488.196 us; speedup vs baseline: 1.3505x; 1.0660x over previous
//
#include <hip/hip_runtime.h>
#include <stdint.h>

// Instant-NGP HashGrid forward, MI355X. Gather-bound.
// R5: baseline 394us; all pipes <40% -> bound by L2 request rate per XCD.
// R6/R7/R8 FAILED: per-wave ILP unraisable (compiler sinks loads or spills).
// R9: XCD level-affinity -> FETCH 440->203MB, L2 req rate 10.3->11.9/cy
//     with hit rate, but 8/8 level split work-imbalanced -> 420us.
// R10 FAILED: hipLaunchCooperativeKernel silently rejected (unchecked rc,
//     co-residency reservation) -> zeros. Lesson: check launch modes.
// R11: same phase-locking via TWO plain stream-ordered launches. Kernel A =
//     levels 0-7 (2.9MB hashed working set < 4MB XCD L2) for all points;
//     kernel B = levels 8-15 (4.0MB). Stream order gives global temporal
//     separation; perfect work balance; no barrier machinery. Each phase
//     stores its 64B half-line per point.

#define NLVL 16
#define TS 65536
#define P2 2654435761u
#define P3 805459861u

typedef float v4f __attribute__((ext_vector_type(4)));
typedef float v2f __attribute__((ext_vector_type(2)));
// 8-byte-aligned float4 view for dense-path table loads.
typedef float v4fa8 __attribute__((ext_vector_type(4), aligned(8)));

__constant__ float C_SCALES[NLVL] = {
    15.0f, 23.0f, 35.0f, 53.0f, 80.0f, 120.5f, 181.25f, 272.375f,
    409.0625f, 614.09375f, 921.640625f, 1382.9609375f,
    2074.94140625f, 3112.912109375f, 4669.8681640625f, 7005.30224609375f};

__device__ __forceinline__ v2f v4lo(v4f v) { v2f r; r.x = v.x; r.y = v.y; return r; }
__device__ __forceinline__ v2f v4hi(v4f v) { v2f r; r.x = v.z; r.y = v.w; return r; }
__device__ __forceinline__ v2f v4lo8(v4fa8 v) { v2f r; r.x = v.x; r.y = v.y; return r; }
__device__ __forceinline__ v2f v4hi8(v4fa8 v) { v2f r; r.x = v.z; r.y = v.w; return r; }

// Half-tile: [256 pts][4 float4 slots]; within-half group gl, half-bit h;
// slot(p,gl) = (gl+p)&3.
__device__ __forceinline__ void lds_put2(float* s, int p, int gl, int h,
                                         float a, float b) {
    const int slot = (gl + p) & 3;
    const int a32 = p * 16 + slot * 4 + h * 2;  // 8B-aligned
    s[a32] = a;
    s[a32 + 1] = b;
}

// One hashed level: returns interpolated (f0,f1). 4 v4f loads + 4
// conditional v2f partner loads (avg 6 line-requests/level).
__device__ __forceinline__ v2f hashed_level(float px, float py, float pz,
                                            float scale, const v2f* tbl) {
    const float fx = px * scale + 0.5f;
    const float fy = py * scale + 0.5f;
    const float fz = pz * scale + 0.5f;
    const float gx = floorf(fx), gy = floorf(fy), gz = floorf(fz);
    const float wx = fx - gx, wy = fy - gy, wz = fz - gz;
    const int ix = (int)gx, iy = (int)gy, iz = (int)gz;

    // h = x ^ y*P2 ^ z*P3 ; even x: h(x+1)=h(x)^1 -> same aligned float4 pair
    const uint32_t bx = (uint32_t)ix;
    const uint32_t hy0 = (uint32_t)iy * P2, hy1 = hy0 + P2;
    const uint32_t hz0 = (uint32_t)iz * P3, hz1 = hz0 + P3;
    const uint32_t b00 = hy0 ^ hz0, b01 = hy0 ^ hz1;
    const uint32_t b10 = hy1 ^ hz0, b11 = hy1 ^ hz1;
    const uint32_t i00 = (bx ^ b00) & (TS - 1);
    const uint32_t i01 = (bx ^ b01) & (TS - 1);
    const uint32_t i10 = (bx ^ b10) & (TS - 1);
    const uint32_t i11 = (bx ^ b11) & (TS - 1);
    const v4f* tbl4 = (const v4f*)tbl;
    const v4f f00 = tbl4[i00 >> 1];
    const v4f f01 = tbl4[i01 >> 1];
    const v4f f10 = tbl4[i10 >> 1];
    const v4f f11 = tbl4[i11 >> 1];
    const v2f c0 = (i00 & 1) ? v4hi(f00) : v4lo(f00);
    const v2f c1 = (i01 & 1) ? v4hi(f01) : v4lo(f01);
    const v2f c2 = (i10 & 1) ? v4hi(f10) : v4lo(f10);
    const v2f c3 = (i11 & 1) ? v4hi(f11) : v4lo(f11);
    v2f c4, c5, c6, c7;
    if ((ix & 1) == 0) {
        c4 = (i00 & 1) ? v4lo(f00) : v4hi(f00);
        c5 = (i01 & 1) ? v4lo(f01) : v4hi(f01);
        c6 = (i10 & 1) ? v4lo(f10) : v4hi(f10);
        c7 = (i11 & 1) ? v4lo(f11) : v4hi(f11);
    } else {
        const uint32_t bx1 = bx + 1;
        c4 = tbl[(bx1 ^ b00) & (TS - 1)];
        c5 = tbl[(bx1 ^ b01) & (TS - 1)];
        c6 = tbl[(bx1 ^ b10) & (TS - 1)];
        c7 = tbl[(bx1 ^ b11) & (TS - 1)];
    }

    const float ux = 1.0f - wx, uy = 1.0f - wy, uz = 1.0f - wz;
    const float w0 = ux * uy * uz, w1 = ux * uy * wz;
    const float w2 = ux * wy * uz, w3 = ux * wy * wz;
    const float w4 = wx * uy * uz, w5 = wx * uy * wz;
    const float w6 = wx * wy * uz, w7 = wx * wy * wz;

    v2f o;
    o.x = w0 * c0.x + w1 * c1.x + w2 * c2.x + w3 * c3.x +
          w4 * c4.x + w5 * c5.x + w6 * c6.x + w7 * c7.x;
    o.y = w0 * c0.y + w1 * c1.y + w2 * c2.y + w3 * c3.y +
          w4 * c4.y + w5 * c5.y + w6 * c6.y + w7 * c7.y;
    return o;
}

// ================= phase A: levels 0..7 -> features 0..15 =================
__global__ __launch_bounds__(256, 8) void hashgrid_fwd_lo(
    const float* __restrict__ x,
    const float* __restrict__ table,
    float* __restrict__ out,
    int n)
{
    __shared__ float s_out[256 * 16];  // 16 KiB half-tile

    const int tid0 = blockIdx.x * 256 + threadIdx.x;
    const int tid = min(tid0, n - 1);
    const int p = threadIdx.x;

    const float px = x[3 * tid + 0];
    const float py = x[3 * tid + 1];
    const float pz = x[3 * tid + 2];

    v4f* outb4 = (v4f*)out + (size_t)blockIdx.x * 2048;
    const long long lim4 = (long long)n * 8 - (long long)blockIdx.x * 2048;

    const v2f* tblv = (const v2f*)table;

    // dense levels 0..2 (small tables, cache-hot), unrolled
    {
        const int RESO[3] = {16, 24, 36};
        const float DSC[3] = {15.0f, 23.0f, 35.0f};
#pragma unroll
        for (int l = 0; l < 3; ++l) {
            const float scale = DSC[l];
            const float fx = px * scale + 0.5f;
            const float fy = py * scale + 0.5f;
            const float fz = pz * scale + 0.5f;
            const float gx = floorf(fx), gy = floorf(fy), gz = floorf(fz);
            const float wx = fx - gx, wy = fy - gy, wz = fz - gz;
            const int ix = (int)gx, iy = (int)gy, iz = (int)gz;

            const v2f* tbl = tblv + (size_t)l * TS;
            const int R = RESO[l];
            const int x0 = min(ix, R - 1);
            const int y0 = min(iy, R - 1), y1 = min(iy + 1, R - 1);
            const int z0 = min(iz, R - 1), z1 = min(iz + 1, R - 1);
            const int xb = min(x0, R - 2);
            const bool hi0 = (x0 != xb);
            const int y0R = y0 * R, y1R = y1 * R;
            const int z0R = z0 * R * R, z1R = z1 * R * R;
            const v4fa8 f00 = *(const v4fa8*)(tbl + (xb + y0R + z0R));
            const v4fa8 f01 = *(const v4fa8*)(tbl + (xb + y0R + z1R));
            const v4fa8 f10 = *(const v4fa8*)(tbl + (xb + y1R + z0R));
            const v4fa8 f11 = *(const v4fa8*)(tbl + (xb + y1R + z1R));
            const v2f c0 = hi0 ? v4hi8(f00) : v4lo8(f00), c4 = v4hi8(f00);
            const v2f c1 = hi0 ? v4hi8(f01) : v4lo8(f01), c5 = v4hi8(f01);
            const v2f c2 = hi0 ? v4hi8(f10) : v4lo8(f10), c6 = v4hi8(f10);
            const v2f c3 = hi0 ? v4hi8(f11) : v4lo8(f11), c7 = v4hi8(f11);

            const float ux = 1.0f - wx, uy = 1.0f - wy, uz = 1.0f - wz;
            const float w0 = ux * uy * uz, w1 = ux * uy * wz;
            const float w2 = ux * wy * uz, w3 = ux * wy * wz;
            const float w4 = wx * uy * uz, w5 = wx * uy * wz;
            const float w6 = wx * wy * uz, w7 = wx * wy * wz;

            const float o0 = w0 * c0.x + w1 * c1.x + w2 * c2.x + w3 * c3.x +
                             w4 * c4.x + w5 * c5.x + w6 * c6.x + w7 * c7.x;
            const float o1 = w0 * c0.y + w1 * c1.y + w2 * c2.y + w3 * c3.y +
                             w4 * c4.y + w5 * c5.y + w6 * c6.y + w7 * c7.y;
            lds_put2(s_out, p, l >> 1, l & 1, o0, o1);
        }
    }
    // hashed levels 3..7
#pragma unroll 2
    for (int l = 3; l < 8; ++l) {
        const v2f o = hashed_level(px, py, pz, C_SCALES[l],
                                   tblv + (size_t)l * TS);
        lds_put2(s_out, p, l >> 1, l & 1, o.x, o.y);
    }
    __syncthreads();
    // store features 0..15 of each point = first 64B line
#pragma unroll
    for (int r = 0; r < 4; ++r) {
        const int e = r * 256 + threadIdx.x;   // 0..1023
        const int pp = e >> 2, g = e & 3;
        const int slot = (g + pp) & 3;
        const v4f v = *(const v4f*)&s_out[pp * 16 + slot * 4];
        const int o4 = pp * 8 + g;
        if (o4 < lim4) outb4[o4] = v;
    }
}

// ================= phase B: levels 8..15 -> features 16..31 =================
__global__ __launch_bounds__(256, 8) void hashgrid_fwd_hi(
    const float* __restrict__ x,
    const float* __restrict__ table,
    float* __restrict__ out,
    int n)
{
    __shared__ float s_out[256 * 16];  // 16 KiB half-tile

    const int tid0 = blockIdx.x * 256 + threadIdx.x;
    const int tid = min(tid0, n - 1);
    const int p = threadIdx.x;

    const float px = x[3 * tid + 0];
    const float py = x[3 * tid + 1];
    const float pz = x[3 * tid + 2];

    v4f* outb4 = (v4f*)out + (size_t)blockIdx.x * 2048;
    const long long lim4 = (long long)n * 8 - (long long)blockIdx.x * 2048;

    const v2f* tblv = (const v2f*)table;

#pragma unroll 2
    for (int l = 8; l < NLVL; ++l) {
        const v2f o = hashed_level(px, py, pz, C_SCALES[l],
                                   tblv + (size_t)l * TS);
        lds_put2(s_out, p, (l >> 1) - 4, l & 1, o.x, o.y);
    }
    __syncthreads();
    // store features 16..31 of each point = second 64B line
#pragma unroll
    for (int r = 0; r < 4; ++r) {
        const int e = r * 256 + threadIdx.x;
        const int pp = e >> 2, g = e & 3;
        const int slot = (g + pp) & 3;
        const v4f v = *(const v4f*)&s_out[pp * 16 + slot * 4];
        const int o4 = pp * 8 + 4 + g;
        if (o4 < lim4) outb4[o4] = v;
    }
}

extern "C" void kernel_launch(void* const* d_in, const int* in_sizes, int n_in,
                              void* d_out, int out_size, void* d_ws, size_t ws_size,
                              hipStream_t stream) {
    const float* x = (const float*)d_in[0];     // [N,3] f32
    const float* table = (const float*)d_in[1]; // [16,65536,2] f32
    float* out = (float*)d_out;                 // [N,32] f32
    const int n = in_sizes[0] / 3;
    const int block = 256;
    const int grid = (n + block - 1) / block;
    hashgrid_fwd_lo<<<grid, block, 0, stream>>>(x, table, out, n);
    hashgrid_fwd_hi<<<grid, block, 0, stream>>>(x, table, out, n);
}